// Round 1
// baseline (478.528 us; speedup 1.0000x reference)
//
#include <hip/hip_runtime.h>
#include <hip/hip_bf16.h>

// CrossAttention: q = x@Wq+bq; k = cond@Wk+bk; v = cond@Wv+bv
// scores = q@k^T (UNSCALED); attn = softmax(scores); out = attn@v
// B=4, Lq=Lk=4096, IN=COND=256, OUT_DIM=128. Output fp32.

typedef __attribute__((ext_vector_type(8))) short short8;
typedef __attribute__((ext_vector_type(8))) unsigned short ushort8;
typedef __attribute__((ext_vector_type(4))) float f32x4;
typedef __bf16 bf16x8 __attribute__((ext_vector_type(8)));

constexpr int BATCH  = 4;
constexpr int SEQLEN = 4096;   // Lq == Lk
constexpr int DIN    = 256;
constexpr int DOUT   = 128;
constexpr int ROWS   = BATCH * SEQLEN;  // 16384

static __device__ __forceinline__ unsigned short bf16_rn(float f) {
  unsigned int u = __builtin_bit_cast(unsigned int, f);
  unsigned int r = u + 0x7FFFu + ((u >> 16) & 1u);
  return (unsigned short)(r >> 16);
}

static __device__ __forceinline__ f32x4 mfma_bf16(short8 a, short8 b, f32x4 c) {
  return __builtin_amdgcn_mfma_f32_16x16x32_bf16(
      __builtin_bit_cast(bf16x8, a), __builtin_bit_cast(bf16x8, b), c, 0, 0, 0);
}

// ---------------- projection: q/k/v = src @ W + b -------------------------
// grid (ROWS/16, 3), block 256. which: 0->q(bf16 [ROWS][128]),
// 1->k(bf16 [ROWS][128]), 2->v stored TRANSPOSED: vt[b][d][l] bf16.
__global__ __launch_bounds__(256) void proj_kernel(
    const float* __restrict__ x, const float* __restrict__ cond,
    const float* __restrict__ Wq, const float* __restrict__ bq,
    const float* __restrict__ Wk, const float* __restrict__ bk,
    const float* __restrict__ Wv, const float* __restrict__ bv,
    unsigned short* __restrict__ qb, unsigned short* __restrict__ kb,
    unsigned short* __restrict__ vt)
{
  const int which = blockIdx.y;
  const float* __restrict__ src  = (which == 0) ? x  : cond;
  const float* __restrict__ W    = (which == 0) ? Wq : (which == 1 ? Wk : Wv);
  const float* __restrict__ bias = (which == 0) ? bq : (which == 1 ? bk : bv);
  const int r0 = blockIdx.x * 16;

  __shared__ __align__(16) float a[16][DIN];   // 16 rows x 256 f32 = 16KB
  {
    const float4* srcv = (const float4*)(src + (size_t)r0 * DIN);
    float4* av = (float4*)&a[0][0];
    #pragma unroll
    for (int i = 0; i < 4; ++i)
      av[threadIdx.x + i * 256] = srcv[threadIdx.x + i * 256];
  }
  __syncthreads();

  const int col  = threadIdx.x & 127;
  const int rsub = (threadIdx.x >> 7) * 8;   // rows rsub..rsub+7
  float acc[8] = {0.f,0.f,0.f,0.f,0.f,0.f,0.f,0.f};

  #pragma unroll 2
  for (int k4 = 0; k4 < DIN / 4; ++k4) {
    const float w0 = W[(k4*4+0)*DOUT + col];
    const float w1 = W[(k4*4+1)*DOUT + col];
    const float w2 = W[(k4*4+2)*DOUT + col];
    const float w3 = W[(k4*4+3)*DOUT + col];
    #pragma unroll
    for (int j = 0; j < 8; ++j) {
      const float4 av = *(const float4*)&a[rsub + j][k4*4];
      acc[j] += av.x * w0;
      acc[j] += av.y * w1;
      acc[j] += av.z * w2;
      acc[j] += av.w * w3;
    }
  }
  const float bb = bias[col];
  #pragma unroll
  for (int j = 0; j < 8; ++j) acc[j] += bb;

  if (which < 2) {
    unsigned short* dst = (which == 0) ? qb : kb;
    #pragma unroll
    for (int j = 0; j < 8; ++j)
      dst[(size_t)(r0 + rsub + j) * DOUT + col] = bf16_rn(acc[j]);
  } else {
    const int g  = r0 + rsub;         // global row
    const int b  = g >> 12;           // /4096
    const int l  = g & (SEQLEN - 1);
    ushort8 pk;
    #pragma unroll
    for (int j = 0; j < 8; ++j) pk[j] = bf16_rn(acc[j]);
    *(ushort8*)(vt + ((size_t)b * DOUT + col) * SEQLEN + l) = pk;
  }
}

// ---------------- flash attention ----------------------------------------
constexpr int QBLK  = 32;   // per block (2 waves x 16 rows)
constexpr int KVBLK = 64;

__global__ __launch_bounds__(128) void attn_kernel(
    const unsigned short* __restrict__ qb,
    const unsigned short* __restrict__ kb,
    const unsigned short* __restrict__ vt,
    float* __restrict__ out)
{
  const int bid  = blockIdx.x;
  const int qt   = bid & (SEQLEN / QBLK - 1);   // 128 q-tiles per batch
  const int b    = bid >> 7;
  const int wid  = threadIdx.x >> 6;
  const int lane = threadIdx.x & 63;
  const int g    = lane >> 4;   // 4 lane-groups
  const int c    = lane & 15;

  // XOR-swizzled LDS tiles: byte ^= ((row&7)<<4)  (G4 / T2 fix)
  __shared__ __align__(16) unsigned short Kt[KVBLK * 128];   // K rows x d, 16KB
  __shared__ __align__(16) unsigned short Vt[128 * KVBLK];   // d x K cols, 16KB
  __shared__ __align__(16) unsigned short Pt[2][16 * KVBLK]; // per-wave P bounce

  // Q fragments: lane holds Q[row=c][k0=dc*32+g*8 .. +8]
  short8 qf[4];
  {
    const unsigned short* qp =
        qb + (size_t)(b * SEQLEN + qt * QBLK + wid * 16 + c) * DOUT;
    #pragma unroll
    for (int dc = 0; dc < 4; ++dc)
      qf[dc] = *(const short8*)(qp + dc * 32 + g * 8);
  }

  f32x4 acc[8];
  #pragma unroll
  for (int dt = 0; dt < 8; ++dt) acc[dt] = (f32x4){0.f, 0.f, 0.f, 0.f};
  float mrow[4] = {-1e30f, -1e30f, -1e30f, -1e30f};
  float lrow[4] = {0.f, 0.f, 0.f, 0.f};

  const char* kbp = (const char*)(kb + (size_t)b * SEQLEN * DOUT);
  const char* vbp = (const char*)(vt + (size_t)b * DOUT * SEQLEN);
  unsigned short* pw = &Pt[wid][0];

  for (int t = 0; t < SEQLEN / KVBLK; ++t) {
    const int kbase = t * KVBLK;
    __syncthreads();   // prev iteration's K/V reads complete
    {
      // K tile: 64 rows x 256B, 16B chunks, swizzled
      const char* ksrc = kbp + (size_t)kbase * 256;
      #pragma unroll
      for (int ii = 0; ii < 8; ++ii) {
        const int i = threadIdx.x + ii * 128;
        const int row = i >> 4, cb = (i & 15) * 16;
        const ushort8 v = *(const ushort8*)(ksrc + row * 256 + cb);
        *(ushort8*)((char*)Kt + ((row * 256 + cb) ^ ((row & 7) << 4))) = v;
      }
      // V^T tile: 128 rows(d) x 128B, swizzled
      const char* vsrc = vbp + (size_t)kbase * 2;
      #pragma unroll
      for (int ii = 0; ii < 8; ++ii) {
        const int i = threadIdx.x + ii * 128;
        const int d = i >> 3, cb = (i & 7) * 16;
        const ushort8 v = *(const ushort8*)(vsrc + (size_t)d * 8192 + cb);
        *(ushort8*)((char*)Vt + ((d * 128 + cb) ^ ((d & 7) << 4))) = v;
      }
    }
    __syncthreads();

    // S = Q K^T  (16 q-rows x 64 keys per wave)
    f32x4 s[4];
    #pragma unroll
    for (int nt = 0; nt < 4; ++nt) {
      s[nt] = (f32x4){0.f, 0.f, 0.f, 0.f};
      const int row = nt * 16 + c;
      const int sw  = (row & 7) << 4;
      #pragma unroll
      for (int dc = 0; dc < 4; ++dc) {
        const short8 bf = *(const short8*)(
            (const char*)Kt + ((row * 256 + dc * 64 + g * 16) ^ sw));
        s[nt] = mfma_bf16(qf[dc], bf, s[nt]);
      }
    }

    // online softmax (rows = g*4 + r; reduce across 16 lanes = 16 keys x 4 tiles)
    #pragma unroll
    for (int r = 0; r < 4; ++r) {
      float tm = fmaxf(fmaxf(s[0][r], s[1][r]), fmaxf(s[2][r], s[3][r]));
      tm = fmaxf(tm, __shfl_xor(tm, 1));
      tm = fmaxf(tm, __shfl_xor(tm, 2));
      tm = fmaxf(tm, __shfl_xor(tm, 4));
      tm = fmaxf(tm, __shfl_xor(tm, 8));
      const float mnew  = fmaxf(mrow[r], tm);
      const float scale = __expf(mrow[r] - mnew);
      mrow[r] = mnew;
      float rs = 0.f;
      #pragma unroll
      for (int nt = 0; nt < 4; ++nt) {
        const float p = __expf(s[nt][r] - mnew);
        s[nt][r] = p;
        rs += p;
      }
      rs += __shfl_xor(rs, 1);
      rs += __shfl_xor(rs, 2);
      rs += __shfl_xor(rs, 4);
      rs += __shfl_xor(rs, 8);
      lrow[r] = lrow[r] * scale + rs;
      #pragma unroll
      for (int dt = 0; dt < 8; ++dt) acc[dt][r] *= scale;
    }

    // P -> LDS (C-layout -> A-layout bounce), swizzled
    #pragma unroll
    for (int nt = 0; nt < 4; ++nt) {
      #pragma unroll
      for (int r = 0; r < 4; ++r) {
        const int prow = g * 4 + r;
        *(unsigned short*)((char*)pw +
            ((prow * 128 + (nt * 16 + c) * 2) ^ ((prow & 7) << 4))) =
            bf16_rn(s[nt][r]);
      }
    }

    // O += P V   (A from Pt, B from Vt; same-wave LDS ordering via lgkmcnt)
    #pragma unroll
    for (int kc = 0; kc < 2; ++kc) {
      const short8 pa = *(const short8*)(
          (const char*)pw + ((c * 128 + kc * 64 + g * 16) ^ ((c & 7) << 4)));
      #pragma unroll
      for (int dt = 0; dt < 8; ++dt) {
        const int d = dt * 16 + c;
        const short8 vb = *(const short8*)(
            (const char*)Vt + ((d * 128 + kc * 64 + g * 16) ^ ((d & 7) << 4)));
        acc[dt] = mfma_bf16(pa, vb, acc[dt]);
      }
    }
  }

  // epilogue: out[b][q][d] = acc / l   (fp32)
  float* op = out + ((size_t)b * SEQLEN + qt * QBLK + wid * 16) * DOUT;
  #pragma unroll
  for (int r = 0; r < 4; ++r) {
    const float inv = 1.f / lrow[r];
    const int qr = g * 4 + r;
    #pragma unroll
    for (int dt = 0; dt < 8; ++dt)
      op[(size_t)qr * DOUT + dt * 16 + c] = acc[dt][r] * inv;
  }
}

extern "C" void kernel_launch(void* const* d_in, const int* in_sizes, int n_in,
                              void* d_out, int out_size, void* d_ws, size_t ws_size,
                              hipStream_t stream) {
  const float* x    = (const float*)d_in[0];
  const float* cond = (const float*)d_in[1];
  const float* Wq   = (const float*)d_in[2];
  const float* bq   = (const float*)d_in[3];
  const float* Wk   = (const float*)d_in[4];
  const float* bk   = (const float*)d_in[5];
  const float* Wv   = (const float*)d_in[6];
  const float* bv   = (const float*)d_in[7];
  float* out = (float*)d_out;

  unsigned short* qb = (unsigned short*)d_ws;                       // 4MB
  unsigned short* kb = qb + (size_t)ROWS * DOUT;                    // 4MB
  unsigned short* vt = kb + (size_t)ROWS * DOUT;                    // 4MB

  proj_kernel<<<dim3(ROWS / 16, 3), 256, 0, stream>>>(
      x, cond, Wq, bq, Wk, bk, Wv, bv, qb, kb, vt);

  attn_kernel<<<dim3(BATCH * (SEQLEN / QBLK)), 128, 0, stream>>>(
      qb, kb, vt, out);
}

// Round 2
// 195.623 us; speedup vs baseline: 2.4462x; 2.4462x over previous
//
#include <hip/hip_runtime.h>
#include <hip/hip_bf16.h>

// CrossAttention: q = x@Wq+bq; k = cond@Wk+bk; v = cond@Wv+bv
// scores = q@k^T (UNSCALED); attn = softmax(scores); out = attn@v
// B=4, Lq=Lk=4096, IN=COND=256, OUT_DIM=128. Output fp32.

typedef __attribute__((ext_vector_type(8))) short short8;
typedef __attribute__((ext_vector_type(8))) unsigned short ushort8;
typedef __attribute__((ext_vector_type(4))) float f32x4;
typedef __bf16 bf16x8 __attribute__((ext_vector_type(8)));

constexpr int BATCH  = 4;
constexpr int SEQLEN = 4096;   // Lq == Lk
constexpr int DIN    = 256;
constexpr int DOUT   = 128;
constexpr int ROWS   = BATCH * SEQLEN;  // 16384

static __device__ __forceinline__ unsigned short bf16_rn(float f) {
  unsigned int u = __builtin_bit_cast(unsigned int, f);
  unsigned int r = u + 0x7FFFu + ((u >> 16) & 1u);
  return (unsigned short)(r >> 16);
}

static __device__ __forceinline__ f32x4 mfma_bf16(short8 a, short8 b, f32x4 c) {
  return __builtin_amdgcn_mfma_f32_16x16x32_bf16(
      __builtin_bit_cast(bf16x8, a), __builtin_bit_cast(bf16x8, b), c, 0, 0, 0);
}

// swizzles: row-stride-256B tiles (K) and row-stride-64B tiles (V^T, P)
static __device__ __forceinline__ int swz256(int a) {
  return a ^ (((a >> 8) & 7) << 4);   // mask bits 4-6 from row bits 0-2; involution
}
static __device__ __forceinline__ int swz64(int a) {
  return a ^ (((a >> 6) & 7) << 4);   // bijective (invertible top-down); write&read both use it
}

// ---------------- projection: q/k/v = src @ W + b -------------------------
// grid (ROWS/16, 3), block 256. which: 0->q(bf16 [ROWS][128]),
// 1->k(bf16 [ROWS][128]), 2->v stored TRANSPOSED: vt[b][d][l] bf16.
__global__ __launch_bounds__(256) void proj_kernel(
    const float* __restrict__ x, const float* __restrict__ cond,
    const float* __restrict__ Wq, const float* __restrict__ bq,
    const float* __restrict__ Wk, const float* __restrict__ bk,
    const float* __restrict__ Wv, const float* __restrict__ bv,
    unsigned short* __restrict__ qb, unsigned short* __restrict__ kb,
    unsigned short* __restrict__ vt)
{
  const int which = blockIdx.y;
  const float* __restrict__ src  = (which == 0) ? x  : cond;
  const float* __restrict__ W    = (which == 0) ? Wq : (which == 1 ? Wk : Wv);
  const float* __restrict__ bias = (which == 0) ? bq : (which == 1 ? bk : bv);
  const int r0 = blockIdx.x * 16;

  __shared__ __align__(16) float a[16][DIN];   // 16 rows x 256 f32 = 16KB
  {
    const float4* srcv = (const float4*)(src + (size_t)r0 * DIN);
    float4* av = (float4*)&a[0][0];
    #pragma unroll
    for (int i = 0; i < 4; ++i)
      av[threadIdx.x + i * 256] = srcv[threadIdx.x + i * 256];
  }
  __syncthreads();

  const int col  = threadIdx.x & 127;
  const int rsub = (threadIdx.x >> 7) * 8;   // rows rsub..rsub+7
  float acc[8] = {0.f,0.f,0.f,0.f,0.f,0.f,0.f,0.f};

  #pragma unroll 2
  for (int k4 = 0; k4 < DIN / 4; ++k4) {
    const float w0 = W[(k4*4+0)*DOUT + col];
    const float w1 = W[(k4*4+1)*DOUT + col];
    const float w2 = W[(k4*4+2)*DOUT + col];
    const float w3 = W[(k4*4+3)*DOUT + col];
    #pragma unroll
    for (int j = 0; j < 8; ++j) {
      const float4 av = *(const float4*)&a[rsub + j][k4*4];
      acc[j] += av.x * w0;
      acc[j] += av.y * w1;
      acc[j] += av.z * w2;
      acc[j] += av.w * w3;
    }
  }
  const float bb = bias[col];
  #pragma unroll
  for (int j = 0; j < 8; ++j) acc[j] += bb;

  if (which < 2) {
    unsigned short* dst = (which == 0) ? qb : kb;
    #pragma unroll
    for (int j = 0; j < 8; ++j)
      dst[(size_t)(r0 + rsub + j) * DOUT + col] = bf16_rn(acc[j]);
  } else {
    const int g  = r0 + rsub;         // global row
    const int b  = g >> 12;           // /4096
    const int l  = g & (SEQLEN - 1);
    ushort8 pk;
    #pragma unroll
    for (int j = 0; j < 8; ++j) pk[j] = bf16_rn(acc[j]);
    *(ushort8*)(vt + ((size_t)b * DOUT + col) * SEQLEN + l) = pk;
  }
}

// ---------------- flash attention, split-KV within block ------------------
// Block: 512 thr = 8 waves = 2 q-subtiles x 4 kv-splits.
// Wave (qsub, split): 16 q-rows x 1024 keys, KVBLK=32 per iteration (32 iters).
// Grid: 512 blocks = 2 blocks/CU exactly; LDS 73KB -> 2 blocks/CU -> 16 waves/CU.
constexpr int NSPLIT = 4;
constexpr int QBLK   = 32;
constexpr int KVBLK  = 32;
constexpr int ITERS  = SEQLEN / NSPLIT / KVBLK;   // 32

__global__ __launch_bounds__(512, 4) void attn_kernel(
    const unsigned short* __restrict__ qb,
    const unsigned short* __restrict__ kb,
    const unsigned short* __restrict__ vt,
    float* __restrict__ out)
{
  // carved LDS: Kt 32KB | Vt 32KB | Pt 8KB | Ml 1KB  (combine reuses Kt/Vt area)
  __shared__ __align__(16) char smem[74752];
  unsigned short* const KtBase = (unsigned short*)smem;
  unsigned short* const VtBase = (unsigned short*)(smem + 32768);
  unsigned short* const PtBase = (unsigned short*)(smem + 65536);
  float (*const Ml)[16][2] = (float(*)[16][2])(smem + 73728);

  const int bid   = blockIdx.x;
  const int qt    = bid & (SEQLEN / QBLK - 1);   // 128 q-tiles per batch
  const int b     = bid >> 7;
  const int tid   = threadIdx.x;
  const int wid   = tid >> 6;
  const int lane  = tid & 63;
  const int split = wid >> 1;
  const int qsub  = wid & 1;
  const int g     = lane >> 4;
  const int c     = lane & 15;
  const int tid128 = tid & 127;    // index within the split's 2-wave group

  char* const Kt = (char*)(KtBase + split * (KVBLK * 128));  // 32 rows x 256B
  char* const Vt = (char*)(VtBase + split * (128 * KVBLK));  // 128 rows x 64B
  char* const Pw = (char*)(PtBase + wid * (16 * KVBLK));     // 16 rows x 64B

  // Q fragments: lane holds Q[row=c][k0=dc*32+g*8 .. +8]
  short8 qf[4];
  {
    const unsigned short* qp =
        qb + (size_t)(b * SEQLEN + qt * QBLK + qsub * 16 + c) * DOUT;
    #pragma unroll
    for (int dc = 0; dc < 4; ++dc)
      qf[dc] = *(const short8*)(qp + dc * 32 + g * 8);
  }

  f32x4 acc[8];
  #pragma unroll
  for (int dt = 0; dt < 8; ++dt) acc[dt] = (f32x4){0.f, 0.f, 0.f, 0.f};
  float mrow[4] = {-1e30f, -1e30f, -1e30f, -1e30f};
  float lrow[4] = {0.f, 0.f, 0.f, 0.f};

  const char* const kbp = (const char*)(kb + (size_t)b * SEQLEN * DOUT);
  const char* const vbp = (const char*)(vt + (size_t)b * DOUT * SEQLEN);
  const int key0 = split * (SEQLEN / NSPLIT);

  for (int t = 0; t < ITERS; ++t) {
    const int kbase = key0 + t * KVBLK;
    __syncthreads();   // prev iteration's LDS reads complete
    {
      // K tile: 32 rows x 256B, 16B chunks (512 chunks / 128 thr = 4 each)
      const char* ksrc = kbp + (size_t)kbase * 256;
      #pragma unroll
      for (int ii = 0; ii < 4; ++ii) {
        const int i = tid128 + ii * 128;
        const int row = i >> 4, cb = (i & 15) * 16;
        const ushort8 v = *(const ushort8*)(ksrc + row * 256 + cb);
        *(ushort8*)(Kt + swz256(row * 256 + cb)) = v;
      }
      // V^T tile: 128 rows(d) x 64B (32 keys)
      const char* vsrc = vbp + (size_t)kbase * 2;
      #pragma unroll
      for (int ii = 0; ii < 4; ++ii) {
        const int i = tid128 + ii * 128;
        const int d = i >> 2, cb = (i & 3) * 16;
        const ushort8 v = *(const ushort8*)(vsrc + (size_t)d * (SEQLEN * 2) + cb);
        *(ushort8*)(Vt + swz64(d * 64 + cb)) = v;
      }
    }
    __syncthreads();

    // S = Q K^T  (16 q-rows x 32 keys per wave)
    f32x4 s[2];
    #pragma unroll
    for (int nt = 0; nt < 2; ++nt) {
      s[nt] = (f32x4){0.f, 0.f, 0.f, 0.f};
      const int row = nt * 16 + c;
      #pragma unroll
      for (int dc = 0; dc < 4; ++dc) {
        const short8 bf = *(const short8*)(Kt + swz256(row * 256 + dc * 64 + g * 16));
        s[nt] = mfma_bf16(qf[dc], bf, s[nt]);
      }
    }

    // online softmax (rows = g*4 + r; reduce across 16 lanes)
    #pragma unroll
    for (int r = 0; r < 4; ++r) {
      float tm = fmaxf(s[0][r], s[1][r]);
      tm = fmaxf(tm, __shfl_xor(tm, 1));
      tm = fmaxf(tm, __shfl_xor(tm, 2));
      tm = fmaxf(tm, __shfl_xor(tm, 4));
      tm = fmaxf(tm, __shfl_xor(tm, 8));
      const float mnew  = fmaxf(mrow[r], tm);
      const float scale = __expf(mrow[r] - mnew);
      mrow[r] = mnew;
      float rs = 0.f;
      #pragma unroll
      for (int nt = 0; nt < 2; ++nt) {
        const float p = __expf(s[nt][r] - mnew);
        s[nt][r] = p;
        rs += p;
      }
      rs += __shfl_xor(rs, 1);
      rs += __shfl_xor(rs, 2);
      rs += __shfl_xor(rs, 4);
      rs += __shfl_xor(rs, 8);
      lrow[r] = lrow[r] * scale + rs;
      #pragma unroll
      for (int dt = 0; dt < 8; ++dt) acc[dt][r] *= scale;
    }

    // P -> LDS (C-layout -> A-layout bounce)
    #pragma unroll
    for (int nt = 0; nt < 2; ++nt) {
      #pragma unroll
      for (int r = 0; r < 4; ++r) {
        const int prow = g * 4 + r;
        *(unsigned short*)(Pw + swz64(prow * 64 + (nt * 16 + c) * 2)) =
            bf16_rn(s[nt][r]);
      }
    }

    // O += P V  (A from Pw, B from Vt; K-dim = 32 keys = one MFMA per dt)
    {
      const short8 pa = *(const short8*)(Pw + swz64(c * 64 + g * 16));
      #pragma unroll
      for (int dt = 0; dt < 8; ++dt) {
        const short8 vb = *(const short8*)(Vt + swz64((dt * 16 + c) * 64 + g * 16));
        acc[dt] = mfma_bf16(pa, vb, acc[dt]);
      }
    }
  }

  // ---------------- cross-split combine in LDS ----------------
  __syncthreads();   // all LDS tile reads done; safe to repurpose
  if (c == 0) {
    #pragma unroll
    for (int r = 0; r < 4; ++r) {
      Ml[wid][g * 4 + r][0] = mrow[r];
      Ml[wid][g * 4 + r][1] = lrow[r];
    }
  }
  __syncthreads();

  float fac[4], lg[4];
  #pragma unroll
  for (int r = 0; r < 4; ++r) {
    const int row = g * 4 + r;
    float mg = -1e30f;
    #pragma unroll
    for (int s2 = 0; s2 < NSPLIT; ++s2)
      mg = fmaxf(mg, Ml[s2 * 2 + qsub][row][0]);
    float lsum = 0.f;
    #pragma unroll
    for (int s2 = 0; s2 < NSPLIT; ++s2)
      lsum += Ml[s2 * 2 + qsub][row][1] * __expf(Ml[s2 * 2 + qsub][row][0] - mg);
    fac[r] = __expf(mrow[r] - mg);
    lg[r]  = lsum;
  }
  #pragma unroll
  for (int dt = 0; dt < 8; ++dt)
    #pragma unroll
    for (int r = 0; r < 4; ++r) acc[dt][r] *= fac[r];

  float* const comb = (float*)smem;   // 6 regions x 16x128 f32 = 48KB (in Kt/Vt area)
  if (split != 0) {
    float* reg = comb + ((split - 1) * 2 + qsub) * (16 * 128);
    #pragma unroll
    for (int dt = 0; dt < 8; ++dt)
      #pragma unroll
      for (int r = 0; r < 4; ++r)
        reg[(g * 4 + r) * 128 + dt * 16 + c] = acc[dt][r];
  }
  __syncthreads();

  if (split == 0) {
    #pragma unroll
    for (int s2 = 1; s2 < NSPLIT; ++s2) {
      const float* reg = comb + ((s2 - 1) * 2 + qsub) * (16 * 128);
      #pragma unroll
      for (int dt = 0; dt < 8; ++dt)
        #pragma unroll
        for (int r = 0; r < 4; ++r)
          acc[dt][r] += reg[(g * 4 + r) * 128 + dt * 16 + c];
    }
    float* const op = out + ((size_t)b * SEQLEN + qt * QBLK + qsub * 16) * DOUT;
    #pragma unroll
    for (int r = 0; r < 4; ++r) {
      const float inv = 1.f / lg[r];
      const int qr = g * 4 + r;
      #pragma unroll
      for (int dt = 0; dt < 8; ++dt)
        op[(size_t)qr * DOUT + dt * 16 + c] = acc[dt][r] * inv;
    }
  }
}

extern "C" void kernel_launch(void* const* d_in, const int* in_sizes, int n_in,
                              void* d_out, int out_size, void* d_ws, size_t ws_size,
                              hipStream_t stream) {
  const float* x    = (const float*)d_in[0];
  const float* cond = (const float*)d_in[1];
  const float* Wq   = (const float*)d_in[2];
  const float* bq   = (const float*)d_in[3];
  const float* Wk   = (const float*)d_in[4];
  const float* bk   = (const float*)d_in[5];
  const float* Wv   = (const float*)d_in[6];
  const float* bv   = (const float*)d_in[7];
  float* out = (float*)d_out;

  unsigned short* qb = (unsigned short*)d_ws;                       // 4MB
  unsigned short* kb = qb + (size_t)ROWS * DOUT;                    // 4MB
  unsigned short* vt = kb + (size_t)ROWS * DOUT;                    // 4MB

  proj_kernel<<<dim3(ROWS / 16, 3), 256, 0, stream>>>(
      x, cond, Wq, bq, Wk, bk, Wv, bv, qb, kb, vt);

  attn_kernel<<<dim3(BATCH * (SEQLEN / QBLK)), 512, 0, stream>>>(
      qb, kb, vt, out);
}

// Round 3
// 171.252 us; speedup vs baseline: 2.7943x; 1.1423x over previous
//
#include <hip/hip_runtime.h>
#include <hip/hip_bf16.h>

// CrossAttention: q = x@Wq+bq; k = cond@Wk+bk; v = cond@Wv+bv
// scores = q@k^T (UNSCALED); attn = softmax(scores); out = attn@v
// B=4, Lq=Lk=4096, IN=COND=256, OUT_DIM=128. Output fp32.

typedef __attribute__((ext_vector_type(8))) short short8;
typedef __attribute__((ext_vector_type(8))) unsigned short ushort8;
typedef __attribute__((ext_vector_type(4))) unsigned short us4;
typedef __attribute__((ext_vector_type(4))) float f32x4;
typedef __bf16 bf16x8 __attribute__((ext_vector_type(8)));

constexpr int BATCH  = 4;
constexpr int SEQLEN = 4096;   // Lq == Lk
constexpr int DIN    = 256;
constexpr int DOUT   = 128;
constexpr int ROWS   = BATCH * SEQLEN;  // 16384

static __device__ __forceinline__ unsigned short bf16_rn(float f) {
  unsigned int u = __builtin_bit_cast(unsigned int, f);
  unsigned int r = u + 0x7FFFu + ((u >> 16) & 1u);
  return (unsigned short)(r >> 16);
}

static __device__ __forceinline__ f32x4 mfma_bf16(short8 a, short8 b, f32x4 c) {
  return __builtin_amdgcn_mfma_f32_16x16x32_bf16(
      __builtin_bit_cast(bf16x8, a), __builtin_bit_cast(bf16x8, b), c, 0, 0, 0);
}

// swizzles: row-stride-256B tiles (K) and row-stride-64B tiles (V^T, P)
static __device__ __forceinline__ int swz256(int a) {
  return a ^ (((a >> 8) & 7) << 4);
}
static __device__ __forceinline__ int swz64(int a) {
  return a ^ (((a >> 6) & 7) << 4);   // bijective; write & read both use it
}

// ---------------- projection: q/k/v = src @ W + b -------------------------
__global__ __launch_bounds__(256) void proj_kernel(
    const float* __restrict__ x, const float* __restrict__ cond,
    const float* __restrict__ Wq, const float* __restrict__ bq,
    const float* __restrict__ Wk, const float* __restrict__ bk,
    const float* __restrict__ Wv, const float* __restrict__ bv,
    unsigned short* __restrict__ qb, unsigned short* __restrict__ kb,
    unsigned short* __restrict__ vt)
{
  const int which = blockIdx.y;
  const float* __restrict__ src  = (which == 0) ? x  : cond;
  const float* __restrict__ W    = (which == 0) ? Wq : (which == 1 ? Wk : Wv);
  const float* __restrict__ bias = (which == 0) ? bq : (which == 1 ? bk : bv);
  const int r0 = blockIdx.x * 16;

  __shared__ __align__(16) float a[16][DIN];
  {
    const float4* srcv = (const float4*)(src + (size_t)r0 * DIN);
    float4* av = (float4*)&a[0][0];
    #pragma unroll
    for (int i = 0; i < 4; ++i)
      av[threadIdx.x + i * 256] = srcv[threadIdx.x + i * 256];
  }
  __syncthreads();

  const int col  = threadIdx.x & 127;
  const int rsub = (threadIdx.x >> 7) * 8;
  float acc[8] = {0.f,0.f,0.f,0.f,0.f,0.f,0.f,0.f};

  #pragma unroll 2
  for (int k4 = 0; k4 < DIN / 4; ++k4) {
    const float w0 = W[(k4*4+0)*DOUT + col];
    const float w1 = W[(k4*4+1)*DOUT + col];
    const float w2 = W[(k4*4+2)*DOUT + col];
    const float w3 = W[(k4*4+3)*DOUT + col];
    #pragma unroll
    for (int j = 0; j < 8; ++j) {
      const float4 av = *(const float4*)&a[rsub + j][k4*4];
      acc[j] += av.x * w0;
      acc[j] += av.y * w1;
      acc[j] += av.z * w2;
      acc[j] += av.w * w3;
    }
  }
  const float bb = bias[col];
  #pragma unroll
  for (int j = 0; j < 8; ++j) acc[j] += bb;

  if (which < 2) {
    unsigned short* dst = (which == 0) ? qb : kb;
    #pragma unroll
    for (int j = 0; j < 8; ++j)
      dst[(size_t)(r0 + rsub + j) * DOUT + col] = bf16_rn(acc[j]);
  } else {
    const int g  = r0 + rsub;
    const int b  = g >> 12;
    const int l  = g & (SEQLEN - 1);
    ushort8 pk;
    #pragma unroll
    for (int j = 0; j < 8; ++j) pk[j] = bf16_rn(acc[j]);
    *(ushort8*)(vt + ((size_t)b * DOUT + col) * SEQLEN + l) = pk;
  }
}

// ---------------- flash attention, split-KV within block ------------------
// Block: 512 thr = 8 waves = 2 q-subtiles x 4 kv-splits. KVBLK=32, 32 iters.
// Swapped QK^T: lane owns query col (c) -> softmax m/l lane-local, 4 shfls/iter.
// PV transposed: acc = O^T[d][query], rescale lane-local.
// T14: global->reg loads for t+1 issued before compute of t, LDS write after.
constexpr int NSPLIT = 4;
constexpr int QBLK   = 32;
constexpr int KVBLK  = 32;
constexpr int ITERS  = SEQLEN / NSPLIT / KVBLK;   // 32

__global__ __launch_bounds__(512, 4) void attn_kernel(
    const unsigned short* __restrict__ qb,
    const unsigned short* __restrict__ kb,
    const unsigned short* __restrict__ vt,
    float* __restrict__ out)
{
  // LDS: Kt 32KB | Vt 32KB | Pt 8KB | Ml 1KB  (combine reuses Kt/Vt area)
  __shared__ __align__(16) char smem[74752];
  char* const KtBase = smem;
  char* const VtBase = smem + 32768;
  char* const PtBase = smem + 65536;
  float (*const Ml)[16][2] = (float(*)[16][2])(smem + 73728);

  const int bid    = blockIdx.x;
  const int qt     = bid & (SEQLEN / QBLK - 1);
  const int b      = bid >> 7;
  const int tid    = threadIdx.x;
  const int wid    = tid >> 6;
  const int lane   = tid & 63;
  const int split  = wid >> 1;
  const int qsub   = wid & 1;
  const int g      = lane >> 4;
  const int c      = lane & 15;
  const int tid128 = tid & 127;

  char* const Kt = KtBase + split * 8192;   // 32 key-rows x 256B
  char* const Vt = VtBase + split * 8192;   // 128 d-rows x 64B
  char* const Pw = PtBase + wid * 1024;     // 16 query-rows x 64B

  // Q fragments: lane holds Q[row=c][k0=dc*32+g*8 .. +8]
  short8 qf[4];
  {
    const unsigned short* qp =
        qb + (size_t)(b * SEQLEN + qt * QBLK + qsub * 16 + c) * DOUT;
    #pragma unroll
    for (int dc = 0; dc < 4; ++dc)
      qf[dc] = *(const short8*)(qp + dc * 32 + g * 8);
  }

  const char* const kbp = (const char*)(kb + (size_t)b * SEQLEN * DOUT);
  const char* const vbp = (const char*)(vt + (size_t)b * DOUT * SEQLEN);
  const int key0 = split * (SEQLEN / NSPLIT);

  // staging addresses (fixed per thread)
  int kgo[4], koff[4], voff[4];
  const char* vgb[4];
  #pragma unroll
  for (int ii = 0; ii < 4; ++ii) {
    const int i = tid128 + ii * 128;
    const int krow = i >> 4, kcb = (i & 15) * 16;
    kgo[ii]  = krow * 256 + kcb;
    koff[ii] = swz256(kgo[ii]);
    const int vd = i >> 2, vcb = (i & 3) * 16;
    vgb[ii]  = vbp + (size_t)vd * (SEQLEN * 2) + vcb;
    voff[ii] = swz64(vd * 64 + vcb);
  }

  ushort8 kreg[4], vreg[4];
  auto load_tile = [&](int kbase) {
    const char* ks = kbp + (size_t)kbase * 256;
    #pragma unroll
    for (int ii = 0; ii < 4; ++ii)
      kreg[ii] = *(const ushort8*)(ks + kgo[ii]);
    #pragma unroll
    for (int ii = 0; ii < 4; ++ii)
      vreg[ii] = *(const ushort8*)(vgb[ii] + (size_t)kbase * 2);
  };
  auto store_tile = [&]() {
    #pragma unroll
    for (int ii = 0; ii < 4; ++ii)
      *(ushort8*)(Kt + koff[ii]) = kreg[ii];
    #pragma unroll
    for (int ii = 0; ii < 4; ++ii)
      *(ushort8*)(Vt + voff[ii]) = vreg[ii];
  };

  f32x4 acc[8];
  #pragma unroll
  for (int dt = 0; dt < 8; ++dt) acc[dt] = (f32x4){0.f, 0.f, 0.f, 0.f};
  float mc = -1e30f, lc = 0.f;   // per-lane: query c of this wave's 16

  load_tile(key0);
  store_tile();
  __syncthreads();

  for (int t = 0; t < ITERS; ++t) {
    const bool more = (t + 1 < ITERS);
    if (more) load_tile(key0 + (t + 1) * KVBLK);   // issue early (T14)

    // S^T = K Q^T : s[nt][r] = S[key = nt*16+g*4+r][query c]
    f32x4 s[2];
    #pragma unroll
    for (int nt = 0; nt < 2; ++nt) {
      s[nt] = (f32x4){0.f, 0.f, 0.f, 0.f};
      const int row = nt * 16 + c;   // key row in Kt
      #pragma unroll
      for (int dc = 0; dc < 4; ++dc) {
        const short8 kf = *(const short8*)(Kt + swz256(row * 256 + dc * 64 + g * 16));
        s[nt] = mfma_bf16(kf, qf[dc], s[nt]);
      }
    }

    // online softmax: lane owns query c; reduce across 4 lane-groups (g)
    float tm = fmaxf(fmaxf(fmaxf(s[0][0], s[0][1]), fmaxf(s[0][2], s[0][3])),
                     fmaxf(fmaxf(s[1][0], s[1][1]), fmaxf(s[1][2], s[1][3])));
    tm = fmaxf(tm, __shfl_xor(tm, 16));
    tm = fmaxf(tm, __shfl_xor(tm, 32));
    const float mnew  = fmaxf(mc, tm);
    const float scale = __expf(mc - mnew);
    mc = mnew;
    float p[2][4];
    float rs = 0.f;
    #pragma unroll
    for (int nt = 0; nt < 2; ++nt)
      #pragma unroll
      for (int r = 0; r < 4; ++r) {
        p[nt][r] = __expf(s[nt][r] - mnew);
        rs += p[nt][r];
      }
    rs += __shfl_xor(rs, 16);
    rs += __shfl_xor(rs, 32);
    lc = lc * scale + rs;
    #pragma unroll
    for (int dt = 0; dt < 8; ++dt)
      #pragma unroll
      for (int r = 0; r < 4; ++r) acc[dt][r] *= scale;

    // P -> LDS, packed: row = query c, 4 consecutive keys per b64 write
    #pragma unroll
    for (int nt = 0; nt < 2; ++nt) {
      us4 pk;
      #pragma unroll
      for (int r = 0; r < 4; ++r) pk[r] = bf16_rn(p[nt][r]);
      *(us4*)(Pw + swz64(c * 64 + nt * 32 + g * 8)) = pk;
    }

    // O^T += V^T P^T : acc[dt][r] = O[d = dt*16+g*4+r][query c]
    {
      const short8 pa = *(const short8*)(Pw + swz64(c * 64 + g * 16));
      #pragma unroll
      for (int dt = 0; dt < 8; ++dt) {
        const short8 vf = *(const short8*)(Vt + swz64((dt * 16 + c) * 64 + g * 16));
        acc[dt] = mfma_bf16(vf, pa, acc[dt]);
      }
    }

    __syncthreads();              // all LDS-t reads done
    if (more) store_tile();       // vmcnt auto-wait on kreg/vreg
    __syncthreads();              // LDS t+1 ready
  }

  // ---------------- cross-split combine ----------------
  if (g == 0) { Ml[wid][c][0] = mc; Ml[wid][c][1] = lc; }
  __syncthreads();

  float mg = -1e30f, lsum = 0.f;
  #pragma unroll
  for (int s2 = 0; s2 < NSPLIT; ++s2)
    mg = fmaxf(mg, Ml[s2 * 2 + qsub][c][0]);
  #pragma unroll
  for (int s2 = 0; s2 < NSPLIT; ++s2)
    lsum += Ml[s2 * 2 + qsub][c][1] * __expf(Ml[s2 * 2 + qsub][c][0] - mg);
  const float fac = __expf(mc - mg);
  #pragma unroll
  for (int dt = 0; dt < 8; ++dt)
    #pragma unroll
    for (int r = 0; r < 4; ++r) acc[dt][r] *= fac;

  // partial sums through LDS (stride 129 to avoid bank conflicts)
  float* const comb = (float*)smem;   // 6 regions x 16x129 f32 = 49.5KB
  if (split != 0) {
    float* reg = comb + ((split - 1) * 2 + qsub) * (16 * 129);
    #pragma unroll
    for (int dt = 0; dt < 8; ++dt)
      #pragma unroll
      for (int r = 0; r < 4; ++r)
        reg[c * 129 + dt * 16 + g * 4 + r] = acc[dt][r];
  }
  __syncthreads();

  if (split == 0) {
    #pragma unroll
    for (int s2 = 1; s2 < NSPLIT; ++s2) {
      const float* reg = comb + ((s2 - 1) * 2 + qsub) * (16 * 129);
      #pragma unroll
      for (int dt = 0; dt < 8; ++dt)
        #pragma unroll
        for (int r = 0; r < 4; ++r)
          acc[dt][r] += reg[c * 129 + dt * 16 + g * 4 + r];
    }
    const float inv = 1.f / lsum;
    float* const op = out + ((size_t)b * SEQLEN + qt * QBLK + qsub * 16) * DOUT;
    #pragma unroll
    for (int dt = 0; dt < 8; ++dt)
      #pragma unroll
      for (int r = 0; r < 4; ++r)
        op[(size_t)c * DOUT + dt * 16 + g * 4 + r] = acc[dt][r] * inv;
  }
}

extern "C" void kernel_launch(void* const* d_in, const int* in_sizes, int n_in,
                              void* d_out, int out_size, void* d_ws, size_t ws_size,
                              hipStream_t stream) {
  const float* x    = (const float*)d_in[0];
  const float* cond = (const float*)d_in[1];
  const float* Wq   = (const float*)d_in[2];
  const float* bq   = (const float*)d_in[3];
  const float* Wk   = (const float*)d_in[4];
  const float* bk   = (const float*)d_in[5];
  const float* Wv   = (const float*)d_in[6];
  const float* bv   = (const float*)d_in[7];
  float* out = (float*)d_out;

  unsigned short* qb = (unsigned short*)d_ws;
  unsigned short* kb = qb + (size_t)ROWS * DOUT;
  unsigned short* vt = kb + (size_t)ROWS * DOUT;

  proj_kernel<<<dim3(ROWS / 16, 3), 256, 0, stream>>>(
      x, cond, Wq, bq, Wk, bk, Wv, bv, qb, kb, vt);

  attn_kernel<<<dim3(BATCH * (SEQLEN / QBLK)), 512, 0, stream>>>(
      qb, kb, vt, out);
}

// Round 4
// 141.923 us; speedup vs baseline: 3.3717x; 1.2067x over previous
//
#include <hip/hip_runtime.h>
#include <hip/hip_bf16.h>

// CrossAttention: q = x@Wq+bq; k = cond@Wk+bk; v = cond@Wv+bv
// scores = q@k^T (UNSCALED); attn = softmax(scores); out = attn@v
// B=4, Lq=Lk=4096, IN=COND=256, OUT_DIM=128. Output fp32.

typedef __attribute__((ext_vector_type(8))) short short8;
typedef __attribute__((ext_vector_type(8))) unsigned short ushort8;
typedef __attribute__((ext_vector_type(4))) unsigned short us4;
typedef __attribute__((ext_vector_type(4))) float f32x4;
typedef __bf16 bf16x8 __attribute__((ext_vector_type(8)));

constexpr int BATCH  = 4;
constexpr int SEQLEN = 4096;   // Lq == Lk
constexpr int DIN    = 256;
constexpr int DOUT   = 128;
constexpr int ROWS   = BATCH * SEQLEN;  // 16384

static __device__ __forceinline__ unsigned short bf16_rn(float f) {
  unsigned int u = __builtin_bit_cast(unsigned int, f);
  unsigned int r = u + 0x7FFFu + ((u >> 16) & 1u);
  return (unsigned short)(r >> 16);
}
static __device__ __forceinline__ float bf16_f32(unsigned short h) {
  return __builtin_bit_cast(float, (unsigned int)h << 16);
}

static __device__ __forceinline__ f32x4 mfma_bf16(short8 a, short8 b, f32x4 c) {
  return __builtin_amdgcn_mfma_f32_16x16x32_bf16(
      __builtin_bit_cast(bf16x8, a), __builtin_bit_cast(bf16x8, b), c, 0, 0, 0);
}

// swizzles for row strides 256B / 128B / 64B
static __device__ __forceinline__ int swz256(int a) {
  return a ^ (((a >> 8) & 7) << 4);
}
static __device__ __forceinline__ int swz128(int a) {
  return a ^ (((a >> 7) & 7) << 4);
}
static __device__ __forceinline__ int swz64(int a) {
  return a ^ (((a >> 6) & 7) << 4);   // bijective; write & read both use it
}

// ---------------- projection via MFMA, split-precision --------------------
// out = (A_hi + A_lo) @ W_bf16 + b, f32 accumulate. Error <= fp32-VALU path.
// grid (ROWS/64, 3), block 256 (4 waves x 16 rows).
// which: 0->q(bf16 [ROWS][128]), 1->k same, 2->v transposed vt[b][d][l].
__global__ __launch_bounds__(256) void proj_kernel(
    const float* __restrict__ x, const float* __restrict__ cond,
    const float* __restrict__ Wq, const float* __restrict__ bq,
    const float* __restrict__ Wk, const float* __restrict__ bk,
    const float* __restrict__ Wv, const float* __restrict__ bv,
    unsigned short* __restrict__ qb, unsigned short* __restrict__ kb,
    unsigned short* __restrict__ vt)
{
  const int which = blockIdx.y;
  const float* __restrict__ src  = (which == 0) ? x  : cond;
  const float* __restrict__ W    = (which == 0) ? Wq : (which == 1 ? Wk : Wv);
  const float* __restrict__ bias = (which == 0) ? bq : (which == 1 ? bk : bv);
  const int r0 = blockIdx.x * 64;

  // LDS: Ah [64][64k] 8KB | Al 8KB | Wt [128col][64k] 16KB  (all swz128)
  __shared__ __align__(16) char lds[32768];
  char* const AhB = lds;
  char* const AlB = lds + 8192;
  char* const WtB = lds + 16384;

  const int tid  = threadIdx.x;
  const int wv   = tid >> 6;
  const int lane = tid & 63;
  const int g    = lane >> 4;
  const int c    = lane & 15;

  f32x4 acc[8];
  #pragma unroll
  for (int cf = 0; cf < 8; ++cf) acc[cf] = (f32x4){0.f, 0.f, 0.f, 0.f};

  for (int kt = 0; kt < 4; ++kt) {
    // ---- stage A hi/lo: 64 rows x 64 k ----
    #pragma unroll
    for (int i = 0; i < 4; ++i) {
      const int idx = tid + i * 256;       // 0..1023
      const int row = idx >> 4, f4 = idx & 15;
      const float4 a4 =
          *(const float4*)(src + (size_t)(r0 + row) * DIN + kt * 64 + f4 * 4);
      us4 hi, lo;
      const float av[4] = {a4.x, a4.y, a4.z, a4.w};
      #pragma unroll
      for (int e = 0; e < 4; ++e) {
        hi[e] = bf16_rn(av[e]);
        lo[e] = bf16_rn(av[e] - bf16_f32(hi[e]));
      }
      const int off = swz128(row * 128 + f4 * 8);
      *(us4*)(AhB + off) = hi;
      *(us4*)(AlB + off) = lo;
    }
    // ---- stage W^T bf16: Wt[col][64 k] ----
    {
      const int col = tid & 127, half = tid >> 7;
      #pragma unroll
      for (int j = 0; j < 4; ++j) {
        const int k0 = half * 32 + j * 8;
        ushort8 wb;
        #pragma unroll
        for (int e = 0; e < 8; ++e)
          wb[e] = bf16_rn(W[(size_t)(kt * 64 + k0 + e) * DOUT + col]);
        *(ushort8*)(WtB + swz128(col * 128 + k0 * 2)) = wb;
      }
    }
    __syncthreads();

    #pragma unroll
    for (int ks = 0; ks < 2; ++ks) {
      const int aoff = (wv * 16 + c) * 128 + ks * 64 + g * 16;
      const short8 ah = *(const short8*)(AhB + swz128(aoff));
      const short8 al = *(const short8*)(AlB + swz128(aoff));
      #pragma unroll
      for (int cf = 0; cf < 8; ++cf) {
        const short8 wb =
            *(const short8*)(WtB + swz128((cf * 16 + c) * 128 + ks * 64 + g * 16));
        acc[cf] = mfma_bf16(ah, wb, acc[cf]);
        acc[cf] = mfma_bf16(al, wb, acc[cf]);
      }
    }
    __syncthreads();
  }

  // epilogue: + bias, store
  if (which < 2) {
    unsigned short* const dst = (which == 0) ? qb : kb;
    #pragma unroll
    for (int cf = 0; cf < 8; ++cf) {
      const float bb = bias[cf * 16 + c];
      #pragma unroll
      for (int r = 0; r < 4; ++r)
        dst[(size_t)(r0 + wv * 16 + g * 4 + r) * DOUT + cf * 16 + c] =
            bf16_rn(acc[cf][r] + bb);
    }
  } else {
    const int b  = r0 >> 12;
    const int l0 = (r0 & (SEQLEN - 1)) + wv * 16 + g * 4;
    #pragma unroll
    for (int cf = 0; cf < 8; ++cf) {
      const float bb = bias[cf * 16 + c];
      us4 pk;
      #pragma unroll
      for (int r = 0; r < 4; ++r) pk[r] = bf16_rn(acc[cf][r] + bb);
      *(us4*)(vt + ((size_t)b * DOUT + cf * 16 + c) * SEQLEN + l0) = pk;
    }
  }
}

// ---------------- flash attention, split-KV within block ------------------
// Block: 512 thr = 8 waves = 2 q-subtiles x 4 kv-splits. KVBLK=32, 32 iters.
// Swapped QK^T: lane owns query col c -> softmax lane-local.
// T13 defer-max: rescale only when a tile max exceeds mc+8 (wave-uniform test).
// l accumulates per-lane; g-reduced once at the end.
constexpr int NSPLIT = 4;
constexpr int QBLK   = 32;
constexpr int KVBLK  = 32;
constexpr int ITERS  = SEQLEN / NSPLIT / KVBLK;   // 32

__global__ __launch_bounds__(512, 4) void attn_kernel(
    const unsigned short* __restrict__ qb,
    const unsigned short* __restrict__ kb,
    const unsigned short* __restrict__ vt,
    float* __restrict__ out)
{
  // LDS: Kt 32KB | Vt 32KB | Pt 8KB | Ml 1KB  (combine reuses Kt/Vt area)
  __shared__ __align__(16) char smem[74752];
  char* const KtBase = smem;
  char* const VtBase = smem + 32768;
  char* const PtBase = smem + 65536;
  float (*const Ml)[16][2] = (float(*)[16][2])(smem + 73728);

  const int bid    = blockIdx.x;
  const int qt     = bid & (SEQLEN / QBLK - 1);
  const int b      = bid >> 7;
  const int tid    = threadIdx.x;
  const int wid    = tid >> 6;
  const int lane   = tid & 63;
  const int split  = wid >> 1;
  const int qsub   = wid & 1;
  const int g      = lane >> 4;
  const int c      = lane & 15;
  const int tid128 = tid & 127;

  char* const Kt = KtBase + split * 8192;   // 32 key-rows x 256B
  char* const Vt = VtBase + split * 8192;   // 128 d-rows x 64B
  char* const Pw = PtBase + wid * 1024;     // 16 query-rows x 64B

  // Q fragments: lane holds Q[row=c][k0=dc*32+g*8 .. +8]
  short8 qf[4];
  {
    const unsigned short* qp =
        qb + (size_t)(b * SEQLEN + qt * QBLK + qsub * 16 + c) * DOUT;
    #pragma unroll
    for (int dc = 0; dc < 4; ++dc)
      qf[dc] = *(const short8*)(qp + dc * 32 + g * 8);
  }

  const char* const kbp = (const char*)(kb + (size_t)b * SEQLEN * DOUT);
  const char* const vbp = (const char*)(vt + (size_t)b * DOUT * SEQLEN);
  const int key0 = split * (SEQLEN / NSPLIT);

  // staging addresses (fixed per thread)
  int kgo[4], koff[4], voff[4];
  const char* vgb[4];
  #pragma unroll
  for (int ii = 0; ii < 4; ++ii) {
    const int i = tid128 + ii * 128;
    const int krow = i >> 4, kcb = (i & 15) * 16;
    kgo[ii]  = krow * 256 + kcb;
    koff[ii] = swz256(kgo[ii]);
    const int vd = i >> 2, vcb = (i & 3) * 16;
    vgb[ii]  = vbp + (size_t)vd * (SEQLEN * 2) + vcb;
    voff[ii] = swz64(vd * 64 + vcb);
  }

  ushort8 kreg[4], vreg[4];
  auto load_tile = [&](int kbase) {
    const char* ks = kbp + (size_t)kbase * 256;
    #pragma unroll
    for (int ii = 0; ii < 4; ++ii)
      kreg[ii] = *(const ushort8*)(ks + kgo[ii]);
    #pragma unroll
    for (int ii = 0; ii < 4; ++ii)
      vreg[ii] = *(const ushort8*)(vgb[ii] + (size_t)kbase * 2);
  };
  auto store_tile = [&]() {
    #pragma unroll
    for (int ii = 0; ii < 4; ++ii)
      *(ushort8*)(Kt + koff[ii]) = kreg[ii];
    #pragma unroll
    for (int ii = 0; ii < 4; ++ii)
      *(ushort8*)(Vt + voff[ii]) = vreg[ii];
  };

  f32x4 acc[8];
  #pragma unroll
  for (int dt = 0; dt < 8; ++dt) acc[dt] = (f32x4){0.f, 0.f, 0.f, 0.f};
  float mc = -1e30f, lc = 0.f;   // per-lane; mc kept wave-uniform

  load_tile(key0);
  store_tile();
  __syncthreads();

  for (int t = 0; t < ITERS; ++t) {
    const bool more = (t + 1 < ITERS);
    if (more) load_tile(key0 + (t + 1) * KVBLK);   // issue early (T14)

    // S^T = K Q^T : s[nt][r] = S[key = nt*16+g*4+r][query c]
    f32x4 s[2];
    #pragma unroll
    for (int nt = 0; nt < 2; ++nt) {
      s[nt] = (f32x4){0.f, 0.f, 0.f, 0.f};
      const int row = nt * 16 + c;   // key row in Kt
      #pragma unroll
      for (int dc = 0; dc < 4; ++dc) {
        const short8 kf = *(const short8*)(Kt + swz256(row * 256 + dc * 64 + g * 16));
        s[nt] = mfma_bf16(kf, qf[dc], s[nt]);
      }
    }

    // T13 defer-max softmax: rescale only if some lane's tile-max > mc+8
    float tm = fmaxf(fmaxf(fmaxf(s[0][0], s[0][1]), fmaxf(s[0][2], s[0][3])),
                     fmaxf(fmaxf(s[1][0], s[1][1]), fmaxf(s[1][2], s[1][3])));
    if (!__all(tm <= mc + 8.f)) {
      float tr = tm;
      tr = fmaxf(tr, __shfl_xor(tr, 16));
      tr = fmaxf(tr, __shfl_xor(tr, 32));
      const float mnew  = fmaxf(mc, tr);
      const float scale = __expf(mc - mnew);
      mc = mnew;
      lc *= scale;
      #pragma unroll
      for (int dt = 0; dt < 8; ++dt)
        #pragma unroll
        for (int r = 0; r < 4; ++r) acc[dt][r] *= scale;
    }
    float p[2][4];
    float rs = 0.f;
    #pragma unroll
    for (int nt = 0; nt < 2; ++nt)
      #pragma unroll
      for (int r = 0; r < 4; ++r) {
        p[nt][r] = __expf(s[nt][r] - mc);
        rs += p[nt][r];
      }
    lc += rs;   // per-lane partial; g-reduced after the loop

    // P -> LDS, packed: row = query c, 4 consecutive keys per b64 write
    #pragma unroll
    for (int nt = 0; nt < 2; ++nt) {
      us4 pk;
      #pragma unroll
      for (int r = 0; r < 4; ++r) pk[r] = bf16_rn(p[nt][r]);
      *(us4*)(Pw + swz64(c * 64 + nt * 32 + g * 8)) = pk;
    }

    // O^T += V^T P^T : acc[dt][r] = O[d = dt*16+g*4+r][query c]
    {
      const short8 pa = *(const short8*)(Pw + swz64(c * 64 + g * 16));
      #pragma unroll
      for (int dt = 0; dt < 8; ++dt) {
        const short8 vf = *(const short8*)(Vt + swz64((dt * 16 + c) * 64 + g * 16));
        acc[dt] = mfma_bf16(vf, pa, acc[dt]);
      }
    }

    __syncthreads();              // all LDS-t reads done
    if (more) store_tile();       // vmcnt auto-wait on kreg/vreg
    __syncthreads();              // LDS t+1 ready
  }

  // ---------------- cross-split combine ----------------
  lc += __shfl_xor(lc, 16);      // fold per-lane partials across g (once)
  lc += __shfl_xor(lc, 32);
  if (g == 0) { Ml[wid][c][0] = mc; Ml[wid][c][1] = lc; }
  __syncthreads();

  float mg = -1e30f, lsum = 0.f;
  #pragma unroll
  for (int s2 = 0; s2 < NSPLIT; ++s2)
    mg = fmaxf(mg, Ml[s2 * 2 + qsub][c][0]);
  #pragma unroll
  for (int s2 = 0; s2 < NSPLIT; ++s2)
    lsum += Ml[s2 * 2 + qsub][c][1] * __expf(Ml[s2 * 2 + qsub][c][0] - mg);
  const float fac = __expf(mc - mg);
  #pragma unroll
  for (int dt = 0; dt < 8; ++dt)
    #pragma unroll
    for (int r = 0; r < 4; ++r) acc[dt][r] *= fac;

  // partial sums through LDS (stride 129 to avoid bank conflicts)
  float* const comb = (float*)smem;   // 6 regions x 16x129 f32 = 49.5KB
  if (split != 0) {
    float* reg = comb + ((split - 1) * 2 + qsub) * (16 * 129);
    #pragma unroll
    for (int dt = 0; dt < 8; ++dt)
      #pragma unroll
      for (int r = 0; r < 4; ++r)
        reg[c * 129 + dt * 16 + g * 4 + r] = acc[dt][r];
  }
  __syncthreads();

  if (split == 0) {
    #pragma unroll
    for (int s2 = 1; s2 < NSPLIT; ++s2) {
      const float* reg = comb + ((s2 - 1) * 2 + qsub) * (16 * 129);
      #pragma unroll
      for (int dt = 0; dt < 8; ++dt)
        #pragma unroll
        for (int r = 0; r < 4; ++r)
          acc[dt][r] += reg[c * 129 + dt * 16 + g * 4 + r];
    }
    const float inv = 1.f / lsum;
    float* const op = out + ((size_t)b * SEQLEN + qt * QBLK + qsub * 16) * DOUT;
    #pragma unroll
    for (int dt = 0; dt < 8; ++dt)
      #pragma unroll
      for (int r = 0; r < 4; ++r)
        op[(size_t)c * DOUT + dt * 16 + g * 4 + r] = acc[dt][r] * inv;
  }
}

extern "C" void kernel_launch(void* const* d_in, const int* in_sizes, int n_in,
                              void* d_out, int out_size, void* d_ws, size_t ws_size,
                              hipStream_t stream) {
  const float* x    = (const float*)d_in[0];
  const float* cond = (const float*)d_in[1];
  const float* Wq   = (const float*)d_in[2];
  const float* bq   = (const float*)d_in[3];
  const float* Wk   = (const float*)d_in[4];
  const float* bk   = (const float*)d_in[5];
  const float* Wv   = (const float*)d_in[6];
  const float* bv   = (const float*)d_in[7];
  float* out = (float*)d_out;

  unsigned short* qb = (unsigned short*)d_ws;
  unsigned short* kb = qb + (size_t)ROWS * DOUT;
  unsigned short* vt = kb + (size_t)ROWS * DOUT;

  proj_kernel<<<dim3(ROWS / 64, 3), 256, 0, stream>>>(
      x, cond, Wq, bq, Wk, bk, Wv, bv, qb, kb, vt);

  attn_kernel<<<dim3(BATCH * (SEQLEN / QBLK)), 512, 0, stream>>>(
      qb, kb, vt, out);
}